// Round 4
// baseline (276.928 us; speedup 1.0000x reference)
//
#include <hip/hip_runtime.h>

// QuantLinearFP8: out[m,n] = sum_k x[m,k] * w[n,k] * scale[n, k/128] + bias[n]
// M=64, K=4096, N=11008, G=128.
//
// R7: T4 counted-vmcnt pipeline. The 2-phase loop's __syncthreads drained
// vmcnt(0) every stage, exposing HBM latency. Now: BK=32, quad-buffered LDS
// (4 x 8 KB = same 32 KB -> occupancy stays 4/CU), prefetch distance 2.
// Barrier = asm "s_waitcnt vmcnt(2)" + s_barrier: the 2 newest loads (stage
// s+2) stay in flight ACROSS the barrier; stage s+1's loads (issued a full
// stage ago) are guaranteed drained (vmcnt is oldest-first, so keeping <=2
// retains exactly the s+2 pair). Epilogue/prep unchanged from R6 (atomics
// into bias-initialized out; fused prep).
// ws layout: only xf bf16 (512 KB) at offset 0.

#define Md 64
#define Kd 4096
#define Nd 11008
#define NGROUPS 32
#define BN 64
#define KSPLIT 8
#define KCHUNK (Kd / KSPLIT)     // 512
#define NST (KCHUNK / 32)        // 16 BK=32 stages per chunk
#define NGRP (KCHUNK / 128)      // 4 scale groups per chunk
#define KBC (KCHUNK / 32)        // 16 32-k steps per chunk

typedef __attribute__((ext_vector_type(8))) __bf16 bf16x8;
typedef __attribute__((ext_vector_type(4))) float f32x4;

// blocks [0,128):   xf[kb][t][lane][j] = x[t*16+(lane&15)][kb*32+(lane>>4)*8+j]
// blocks [128,816): out[i] = bias[i % Nd]  (bias pre-init for atomic split-K)
__global__ __launch_bounds__(256)
void prep(const float* __restrict__ x, __bf16* __restrict__ xf,
          const float* __restrict__ bias, float* __restrict__ out)
{
    if (blockIdx.x < 128) {
        const int tid  = blockIdx.x * 256 + threadIdx.x;  // frag id, 32768
        const int lane = tid & 63;
        const int t    = (tid >> 6) & 3;
        const int kb   = tid >> 8;
        const int row  = t * 16 + (lane & 15);
        const int col  = kb * 32 + (lane >> 4) * 8;
        const float4 a = *(const float4*)(x + (size_t)row * Kd + col);
        const float4 b = *(const float4*)(x + (size_t)row * Kd + col + 4);
        bf16x8 v = {(__bf16)a.x, (__bf16)a.y, (__bf16)a.z, (__bf16)a.w,
                    (__bf16)b.x, (__bf16)b.y, (__bf16)b.z, (__bf16)b.w};
        *(bf16x8*)(xf + (size_t)tid * 8) = v;
    } else {
        const int i4 = (blockIdx.x - 128) * 256 + threadIdx.x; // 176128 = Md*Nd/4
        const int n  = (i4 * 4) % Nd;                          // Nd % 4 == 0
        *(float4*)(out + (size_t)i4 * 4) = *(const float4*)(bias + n);
    }
}

__global__ __launch_bounds__(256, 4)
void qlinear_pass1(const float* __restrict__ w,
                   const __bf16* __restrict__ xf,
                   const float* __restrict__ scale,
                   float* __restrict__ out)
{
    const int tid  = threadIdx.x;
    const int wv   = tid >> 6;         // wave -> n-substripe
    const int lane = tid & 63;
    const int quad = lane >> 4;
    const int ln   = lane & 15;

    const int n0 = blockIdx.x * BN;
    const int ky = blockIdx.y;
    const int k0 = ky * KCHUNK;

    __shared__ alignas(16) float lds_w[4][BN * 32];   // 4 x 8 KB

    // staging: 2 issues/wave/stage; issue j covers rows wv*16+j*8 .. +7
    // (8 rows x 128 B contiguous). Source 16B-chunk XOR-swizzled by row so
    // linear LDS holds the swizzled layout (rule 21).
    const float* src[2];
    #pragma unroll
    for (int j = 0; j < 2; ++j) {
        const int r   = wv * 16 + j * 8 + (lane >> 3);   // row this lane feeds
        const int c16 = (lane & 7) ^ (r & 7);            // swizzled chunk 0..7
        src[j] = w + (size_t)(n0 + r) * Kd + k0 + c16 * 4;
    }

#define STAGE(S, B)                                                            \
    do {                                                                       \
        _Pragma("unroll")                                                      \
        for (int j = 0; j < 2; ++j)                                            \
            __builtin_amdgcn_global_load_lds(                                  \
                (const __attribute__((address_space(1))) void*)(src[j] + (S) * 32), \
                (__attribute__((address_space(3))) void*)&lds_w[B][(wv * 16 + j * 8) * 32], \
                16, 0, 0);                                                     \
    } while (0)

    // A-frag source: pre-converted bf16 frags, 16 B per lane per (kb,t)
    const __bf16* xp = xf + (size_t)ky * KBC * 4 * 512 + (size_t)lane * 8;

    const int nrow = n0 + wv * 16 + ln;
    float4 sc4 = *(const float4*)(scale + (size_t)nrow * NGROUPS + ky * NGRP);
    const float sc[4] = {sc4.x, sc4.y, sc4.z, sc4.w};

    // frag-read row + swizzle key
    const int rr = wv * 16 + ln;
    const int rx = rr & 7;

    f32x4 acc[4];
    #pragma unroll
    for (int t = 0; t < 4; ++t) acc[t] = (f32x4){0.f, 0.f, 0.f, 0.f};

    // prologue: stages 0 and 1 in flight; wait stage 0 only (keep 2 newest)
    STAGE(0, 0);
    STAGE(1, 1);
    asm volatile("s_waitcnt vmcnt(2)" ::: "memory");
    __builtin_amdgcn_s_barrier();

    #pragma unroll
    for (int g = 0; g < NGRP; ++g) {
        f32x4 pg[4];
        #pragma unroll
        for (int t = 0; t < 4; ++t) pg[t] = (f32x4){0.f, 0.f, 0.f, 0.f};

        #pragma unroll
        for (int sub = 0; sub < 4; ++sub) {
            const int s   = g * 4 + sub;     // stage 0..15 (compile-time)
            const int buf = s & 3;

            // prefetch stage s+2 (stays in flight across the barrier)
            if (s + 2 < NST) STAGE(s + 2, (s + 2) & 3);

            // x frags for this 32-k step
            bf16x8 xv[4];
            #pragma unroll
            for (int t = 0; t < 4; ++t)
                xv[t] = *(const bf16x8*)(xp + ((size_t)s * 4 + t) * 512);

            // w frag: two swizzled 16B chunks of row rr
            const int cA = (quad * 2) ^ rx;
            const int cB = (quad * 2 + 1) ^ rx;
            f32x4 fa = *(const f32x4*)&lds_w[buf][rr * 32 + cA * 4];
            f32x4 fb = *(const f32x4*)&lds_w[buf][rr * 32 + cB * 4];
            bf16x8 wf = {(__bf16)fa.x, (__bf16)fa.y, (__bf16)fa.z, (__bf16)fa.w,
                         (__bf16)fb.x, (__bf16)fb.y, (__bf16)fb.z, (__bf16)fb.w};

            #pragma unroll
            for (int t = 0; t < 4; ++t)
                pg[t] = __builtin_amdgcn_mfma_f32_16x16x32_bf16(xv[t], wf, pg[t],
                                                                0, 0, 0);

            // counted-vmcnt barrier: keep the s+2 loads in flight
            if (s + 1 < NST) {
                if (s + 2 < NST)
                    asm volatile("s_waitcnt vmcnt(2)" ::: "memory");
                else
                    asm volatile("s_waitcnt vmcnt(0)" ::: "memory");
                __builtin_amdgcn_s_barrier();
            }
        }

        const float s = sc[g];
        #pragma unroll
        for (int t = 0; t < 4; ++t)
            #pragma unroll
            for (int r = 0; r < 4; ++r)
                acc[t][r] += s * pg[t][r];
    }

    // atomic split-K epilogue -> out[m][n]  (C/D: m = t*16+quad*4+r, col = ln)
    float* op = out + n0 + wv * 16 + ln;
    #pragma unroll
    for (int t = 0; t < 4; ++t)
        #pragma unroll
        for (int r = 0; r < 4; ++r)
            unsafeAtomicAdd(&op[(size_t)(t * 16 + quad * 4 + r) * Nd], acc[t][r]);
#undef STAGE
}

extern "C" void kernel_launch(void* const* d_in, const int* in_sizes, int n_in,
                              void* d_out, int out_size, void* d_ws, size_t ws_size,
                              hipStream_t stream) {
    const float* x     = (const float*)d_in[0];  // [64][4096]
    const float* w     = (const float*)d_in[1];  // [11008][4096]
    const float* scale = (const float*)d_in[2];  // [11008][32]
    const float* bias  = (const float*)d_in[3];  // [11008]
    float* out = (float*)d_out;                  // [64][11008] f32
    float* ws  = (float*)d_ws;                   // xf bf16 (512 KB)

    __bf16* xf = (__bf16*)ws;                    // 16B-aligned

    prep<<<816, 256, 0, stream>>>(x, xf, bias, out);

    dim3 grid1(Nd / BN, KSPLIT);
    qlinear_pass1<<<grid1, 256, 0, stream>>>(w, xf, scale, out);
}

// Round 5
// 273.594 us; speedup vs baseline: 1.0122x; 1.0122x over previous
//
#include <hip/hip_runtime.h>

// QuantLinearFP8: out[m,n] = sum_k x[m,k] * w[n,k] * scale[n, k/128] + bias[n]
// M=64, K=4096, N=11008, G=128.
//
// R8: T4 counted-vmcnt with an AIRTIGHT vmcnt window (R7 failed because xv
// global loads polluted the count). Changes vs R6/R7:
//  - x is staged through LDS via global_load_lds too (xf frag layout is
//    lane-linear -> legal dest). The K-loop now has ZERO compiler VMEM ops.
//  - BK=32, triple-buffered (w 3x8KB + x 3x4KB = 36KB -> still 4 blocks/CU),
//    prefetch distance 2. Stage s issues exactly 3 global_load_lds for s+2;
//    barrier = s_waitcnt vmcnt(3) (retain s+2's 3, drain s+1's; oldest-first)
//    + raw s_barrier. WAW safe: (s+2)%3 == (s-1)%3, separated by a barrier.
//  - scale load fenced behind vmcnt(0) before the pipeline (can't sink into
//    the counted window past a memory-clobber asm).
// Epilogue/prep unchanged from R6 (atomics into bias-initialized out).
// ws layout: only xf bf16 (512 KB) at offset 0.

#define Md 64
#define Kd 4096
#define Nd 11008
#define NGROUPS 32
#define BN 64
#define KSPLIT 8
#define KCHUNK (Kd / KSPLIT)     // 512
#define NST (KCHUNK / 32)        // 16 BK=32 stages per chunk
#define NGRP (KCHUNK / 128)      // 4 scale groups per chunk

typedef __attribute__((ext_vector_type(8))) __bf16 bf16x8;
typedef __attribute__((ext_vector_type(4))) float f32x4;

#define AS1 __attribute__((address_space(1)))
#define AS3 __attribute__((address_space(3)))

// blocks [0,128):   xf[kb][t][lane][j] = x[t*16+(lane&15)][kb*32+(lane>>4)*8+j]
// blocks [128,816): out[i] = bias[i % Nd]  (bias pre-init for atomic split-K)
__global__ __launch_bounds__(256)
void prep(const float* __restrict__ x, __bf16* __restrict__ xf,
          const float* __restrict__ bias, float* __restrict__ out)
{
    if (blockIdx.x < 128) {
        const int tid  = blockIdx.x * 256 + threadIdx.x;  // frag id, 32768
        const int lane = tid & 63;
        const int t    = (tid >> 6) & 3;
        const int kb   = tid >> 8;
        const int row  = t * 16 + (lane & 15);
        const int col  = kb * 32 + (lane >> 4) * 8;
        const float4 a = *(const float4*)(x + (size_t)row * Kd + col);
        const float4 b = *(const float4*)(x + (size_t)row * Kd + col + 4);
        bf16x8 v = {(__bf16)a.x, (__bf16)a.y, (__bf16)a.z, (__bf16)a.w,
                    (__bf16)b.x, (__bf16)b.y, (__bf16)b.z, (__bf16)b.w};
        *(bf16x8*)(xf + (size_t)tid * 8) = v;
    } else {
        const int i4 = (blockIdx.x - 128) * 256 + threadIdx.x; // 176128 = Md*Nd/4
        const int n  = (i4 * 4) % Nd;                          // Nd % 4 == 0
        *(float4*)(out + (size_t)i4 * 4) = *(const float4*)(bias + n);
    }
}

__global__ __launch_bounds__(256, 4)
void qlinear_pass1(const float* __restrict__ w,
                   const __bf16* __restrict__ xf,
                   const float* __restrict__ scale,
                   float* __restrict__ out)
{
    const int tid  = threadIdx.x;
    const int wv   = tid >> 6;         // wave -> n-substripe
    const int lane = tid & 63;
    const int quad = lane >> 4;
    const int ln   = lane & 15;

    const int n0 = blockIdx.x * BN;
    const int ky = blockIdx.y;
    const int k0 = ky * KCHUNK;

    __shared__ alignas(16) float  lds_w[3][BN * 32];   // 3 x 8 KB
    __shared__ alignas(16) __bf16 lds_x[3][2048];      // 3 x 4 KB

    // w staging: 2 issues/wave/stage; issue j covers rows wv*16+j*8..+7
    // (8 rows x 128 B contiguous = one full BK=32 row each). Source 16B-chunk
    // XOR-swizzled by row so linear LDS holds the swizzled layout (rule 21).
    const float* src[2];
    #pragma unroll
    for (int j = 0; j < 2; ++j) {
        const int r   = wv * 16 + j * 8 + (lane >> 3);   // row this lane feeds
        const int c16 = (lane & 7) ^ (r & 7);            // swizzled chunk 0..7
        src[j] = w + (size_t)(n0 + r) * Kd + k0 + c16 * 4;
    }

    // x staging: 1 issue/wave/stage. xf element offset for (kb,t,lane) is
    // (kb*4+t)*512 + lane*8 -> lane-linear 16B, legal global_load_lds dest.
    const __bf16* xq = xf + ((size_t)ky * 64 + wv) * 512 + (size_t)lane * 8;

#define STAGE(S, B)                                                            \
    do {                                                                       \
        _Pragma("unroll")                                                      \
        for (int j = 0; j < 2; ++j)                                            \
            __builtin_amdgcn_global_load_lds(                                  \
                (const AS1 void*)(src[j] + (S) * 32),                          \
                (AS3 void*)&lds_w[B][(wv * 16 + j * 8) * 32], 16, 0, 0);       \
        __builtin_amdgcn_global_load_lds(                                      \
            (const AS1 void*)(xq + (size_t)(S) * 2048),                        \
            (AS3 void*)&lds_x[B][wv * 512], 16, 0, 0);                         \
    } while (0)

    // scales: load and fully drain BEFORE the counted pipeline starts
    const int nrow = n0 + wv * 16 + ln;
    float4 sc4 = *(const float4*)(scale + (size_t)nrow * NGROUPS + ky * NGRP);
    asm volatile("s_waitcnt vmcnt(0)" ::: "memory");
    const float sc[4] = {sc4.x, sc4.y, sc4.z, sc4.w};

    // frag-read row + swizzle key
    const int rr = wv * 16 + ln;
    const int rx = rr & 7;

    f32x4 acc[4];
    #pragma unroll
    for (int t = 0; t < 4; ++t) acc[t] = (f32x4){0.f, 0.f, 0.f, 0.f};

    // prologue: stages 0,1 in flight (3 ops each); retain stage 1's 3
    STAGE(0, 0);
    STAGE(1, 1);
    asm volatile("s_waitcnt vmcnt(3)" ::: "memory");
    __builtin_amdgcn_s_barrier();

    #pragma unroll
    for (int g = 0; g < NGRP; ++g) {
        f32x4 pg[4];
        #pragma unroll
        for (int t = 0; t < 4; ++t) pg[t] = (f32x4){0.f, 0.f, 0.f, 0.f};

        #pragma unroll
        for (int sub = 0; sub < 4; ++sub) {
            const int s   = g * 4 + sub;     // stage 0..15 (compile-time)
            const int buf = s % 3;

            // prefetch stage s+2 (its 3 loads stay in flight across barrier)
            if (s + 2 < NST) STAGE(s + 2, (s + 2) % 3);

            // x frags for this 32-k step (from LDS, lgkmcnt domain)
            bf16x8 xv[4];
            #pragma unroll
            for (int t = 0; t < 4; ++t)
                xv[t] = *(const bf16x8*)&lds_x[buf][t * 512 + lane * 8];

            // w frag: two swizzled 16B chunks of row rr
            const int cA = (quad * 2) ^ rx;
            const int cB = (quad * 2 + 1) ^ rx;
            f32x4 fa = *(const f32x4*)&lds_w[buf][rr * 32 + cA * 4];
            f32x4 fb = *(const f32x4*)&lds_w[buf][rr * 32 + cB * 4];
            bf16x8 wf = {(__bf16)fa.x, (__bf16)fa.y, (__bf16)fa.z, (__bf16)fa.w,
                         (__bf16)fb.x, (__bf16)fb.y, (__bf16)fb.z, (__bf16)fb.w};

            #pragma unroll
            for (int t = 0; t < 4; ++t)
                pg[t] = __builtin_amdgcn_mfma_f32_16x16x32_bf16(xv[t], wf, pg[t],
                                                                0, 0, 0);

            // counted barrier: drain s+1's loads, keep s+2's in flight
            if (s + 1 < NST) {
                if (s + 2 < NST)
                    asm volatile("s_waitcnt vmcnt(3)" ::: "memory");
                else
                    asm volatile("s_waitcnt vmcnt(0)" ::: "memory");
                __builtin_amdgcn_s_barrier();
            }
        }

        const float s = sc[g];
        #pragma unroll
        for (int t = 0; t < 4; ++t)
            #pragma unroll
            for (int r = 0; r < 4; ++r)
                acc[t][r] += s * pg[t][r];
    }

    // atomic split-K epilogue -> out[m][n]  (C/D: m = t*16+quad*4+r, col = ln)
    float* op = out + n0 + wv * 16 + ln;
    #pragma unroll
    for (int t = 0; t < 4; ++t)
        #pragma unroll
        for (int r = 0; r < 4; ++r)
            unsafeAtomicAdd(&op[(size_t)(t * 16 + quad * 4 + r) * Nd], acc[t][r]);
#undef STAGE
}

extern "C" void kernel_launch(void* const* d_in, const int* in_sizes, int n_in,
                              void* d_out, int out_size, void* d_ws, size_t ws_size,
                              hipStream_t stream) {
    const float* x     = (const float*)d_in[0];  // [64][4096]
    const float* w     = (const float*)d_in[1];  // [11008][4096]
    const float* scale = (const float*)d_in[2];  // [11008][32]
    const float* bias  = (const float*)d_in[3];  // [11008]
    float* out = (float*)d_out;                  // [64][11008] f32
    float* ws  = (float*)d_ws;                   // xf bf16 (512 KB)

    __bf16* xf = (__bf16*)ws;                    // 16B-aligned

    prep<<<816, 256, 0, stream>>>(x, xf, bias, out);

    dim3 grid1(Nd / BN, KSPLIT);
    qlinear_pass1<<<grid1, 256, 0, stream>>>(w, xf, scale, out);
}

// Round 6
// 267.999 us; speedup vs baseline: 1.0333x; 1.0209x over previous
//
#include <hip/hip_runtime.h>

// QuantLinearFP8: out[m,n] = sum_k x[m,k] * w[n,k] * scale[n, k/128] + bias[n]
// M=64, K=4096, N=11008, G=128.
//
// R9: BARRIER-FREE deep pipeline. Two observations:
//  (1) the w LDS tile is WAVE-PRIVATE (wave wv stages rows [wv*16,wv*16+16)
//      and reads only those rows) -> no cross-wave visibility needed -> all
//      __syncthreads deleted; per-wave vmcnt orders LDS-DMA vs ds_read.
//  (2) mixed prefetch depths are impossible under one in-order vmcnt counter,
//      so x moves to a REGISTER ring prefetched at the same distance-4 as w.
// Per stage s: issue W(s+4) -> s_waitcnt vmcnt(20) (retain stages s+1..s+4 =
// 4x(2 w-ops + 4 x-loads) - stage s's X issued post-compute, so retained set
// is exactly 20; drains stage s) -> ds_read + 4 MFMA -> issue X(s+4) into the
// ring slot just freed. Never vmcnt(0) in steady state; waves fully
// decoupled. w: 5-buffer LDS (5 x 8 KB = 40 KB), XOR-swizzled as R6.
// Scales loaded + drained before the counted window (R8 lesson).
// prep + atomic epilogue unchanged from R6 (best measured).
// ws layout: only xf bf16 (512 KB) at offset 0.

#define Md 64
#define Kd 4096
#define Nd 11008
#define NGROUPS 32
#define BN 64
#define KSPLIT 8
#define KCHUNK (Kd / KSPLIT)     // 512
#define NST (KCHUNK / 32)        // 16 BK=32 stages per chunk
#define NBUF 5                   // w LDS ring
#define DIST 4                   // prefetch distance

typedef __attribute__((ext_vector_type(8))) __bf16 bf16x8;
typedef __attribute__((ext_vector_type(4))) float f32x4;

#define AS1 __attribute__((address_space(1)))
#define AS3 __attribute__((address_space(3)))

// blocks [0,128):   xf[kb][t][lane][j] = x[t*16+(lane&15)][kb*32+(lane>>4)*8+j]
// blocks [128,816): out[i] = bias[i % Nd]  (bias pre-init for atomic split-K)
__global__ __launch_bounds__(256)
void prep(const float* __restrict__ x, __bf16* __restrict__ xf,
          const float* __restrict__ bias, float* __restrict__ out)
{
    if (blockIdx.x < 128) {
        const int tid  = blockIdx.x * 256 + threadIdx.x;  // frag id, 32768
        const int lane = tid & 63;
        const int t    = (tid >> 6) & 3;
        const int kb   = tid >> 8;
        const int row  = t * 16 + (lane & 15);
        const int col  = kb * 32 + (lane >> 4) * 8;
        const float4 a = *(const float4*)(x + (size_t)row * Kd + col);
        const float4 b = *(const float4*)(x + (size_t)row * Kd + col + 4);
        bf16x8 v = {(__bf16)a.x, (__bf16)a.y, (__bf16)a.z, (__bf16)a.w,
                    (__bf16)b.x, (__bf16)b.y, (__bf16)b.z, (__bf16)b.w};
        *(bf16x8*)(xf + (size_t)tid * 8) = v;
    } else {
        const int i4 = (blockIdx.x - 128) * 256 + threadIdx.x; // 176128 = Md*Nd/4
        const int n  = (i4 * 4) % Nd;                          // Nd % 4 == 0
        *(float4*)(out + (size_t)i4 * 4) = *(const float4*)(bias + n);
    }
}

__global__ __launch_bounds__(256, 3)
void qlinear_pass1(const float* __restrict__ w,
                   const __bf16* __restrict__ xf,
                   const float* __restrict__ scale,
                   float* __restrict__ out)
{
    const int tid  = threadIdx.x;
    const int wv   = tid >> 6;         // wave -> n-substripe
    const int lane = tid & 63;
    const int quad = lane >> 4;
    const int ln   = lane & 15;

    const int n0 = blockIdx.x * BN;
    const int ky = blockIdx.y;
    const int k0 = ky * KCHUNK;

    __shared__ alignas(16) float lds_w[NBUF][BN * 32];   // 5 x 8 KB

    // wave-private w staging: 2 issues/stage cover rows wv*16..+15
    // (8 rows x 128 B contiguous each). Source 16B-chunk XOR-swizzled by row
    // so linear LDS holds the swizzled layout (rule 21).
    const float* src[2];
    #pragma unroll
    for (int j = 0; j < 2; ++j) {
        const int r   = wv * 16 + j * 8 + (lane >> 3);   // row this lane feeds
        const int c16 = (lane & 7) ^ (r & 7);            // swizzled chunk 0..7
        src[j] = w + (size_t)(n0 + r) * Kd + k0 + c16 * 4;
    }

#define WSTAGE(S, B)                                                           \
    do {                                                                       \
        _Pragma("unroll")                                                      \
        for (int j = 0; j < 2; ++j)                                           \
            __builtin_amdgcn_global_load_lds(                                  \
                (const AS1 void*)(src[j] + (S) * 32),                          \
                (AS3 void*)&lds_w[B][(wv * 16 + j * 8) * 32], 16, 0, 0);       \
    } while (0)

    // x register ring: 4 frags per stage, prefetched at distance 4
    const __bf16* xp = xf + (size_t)ky * NST * 4 * 512 + (size_t)lane * 8;
    bf16x8 xr[4][4];

#define XLOAD(SLOT, S)                                                         \
    do {                                                                       \
        _Pragma("unroll")                                                      \
        for (int t = 0; t < 4; ++t)                                           \
            xr[SLOT][t] = *(const bf16x8*)(xp + ((size_t)(S) * 4 + t) * 512);  \
    } while (0)

    // scales: load and fully drain BEFORE the counted window starts
    const int nrow = n0 + wv * 16 + ln;
    float4 sc4 = *(const float4*)(scale + (size_t)nrow * NGROUPS + ky * 4);
    asm volatile("s_waitcnt vmcnt(0)" ::: "memory");
    const float sc[4] = {sc4.x, sc4.y, sc4.z, sc4.w};

    // frag-read row + swizzle key
    const int rr = wv * 16 + ln;
    const int rx = rr & 7;

    f32x4 acc[4], pg[4];
    #pragma unroll
    for (int t = 0; t < 4; ++t) {
        acc[t] = (f32x4){0.f, 0.f, 0.f, 0.f};
        pg[t]  = (f32x4){0.f, 0.f, 0.f, 0.f};
    }

    // prologue: stages 0..3 in flight, interleaved W,X (6 ops per stage)
    WSTAGE(0, 0); XLOAD(0, 0);
    WSTAGE(1, 1); XLOAD(1, 1);
    WSTAGE(2, 2); XLOAD(2, 2);
    WSTAGE(3, 3); XLOAD(3, 3);

    #pragma unroll
    for (int s = 0; s < NST; ++s) {
        // issue next w stage (top of window)
        if (s + DIST < NST) WSTAGE(s + DIST, (s + DIST) % NBUF);

        // single counted wait: drains exactly stage s (w pair + x quad),
        // retains stages s+1..s+4. Never 0 until the tail.
        if (s + DIST < NST)      asm volatile("s_waitcnt vmcnt(20)" ::: "memory");
        else if (s == NST - 4)   asm volatile("s_waitcnt vmcnt(18)" ::: "memory");
        else if (s == NST - 3)   asm volatile("s_waitcnt vmcnt(12)" ::: "memory");
        else if (s == NST - 2)   asm volatile("s_waitcnt vmcnt(6)"  ::: "memory");
        else                     asm volatile("s_waitcnt vmcnt(0)"  ::: "memory");
        __builtin_amdgcn_sched_barrier(0);

        // w frag: two swizzled 16B chunks of (wave-private) row rr
        const int buf = s % NBUF;
        const int cA  = (quad * 2) ^ rx;
        const int cB  = (quad * 2 + 1) ^ rx;
        f32x4 fa = *(const f32x4*)&lds_w[buf][rr * 32 + cA * 4];
        f32x4 fb = *(const f32x4*)&lds_w[buf][rr * 32 + cB * 4];
        bf16x8 wf = {(__bf16)fa.x, (__bf16)fa.y, (__bf16)fa.z, (__bf16)fa.w,
                     (__bf16)fb.x, (__bf16)fb.y, (__bf16)fb.z, (__bf16)fb.w};

        #pragma unroll
        for (int t = 0; t < 4; ++t)
            pg[t] = __builtin_amdgcn_mfma_f32_16x16x32_bf16(xr[s & 3][t], wf,
                                                            pg[t], 0, 0, 0);

        // refill the x ring slot just consumed (bottom of window)
        if (s + DIST < NST) XLOAD(s & 3, s + DIST);

        // per-128k scale group boundary: fold pg into acc
        if ((s & 3) == 3) {
            const float sg = sc[s >> 2];
            #pragma unroll
            for (int t = 0; t < 4; ++t) {
                #pragma unroll
                for (int r = 0; r < 4; ++r) {
                    acc[t][r] += sg * pg[t][r];
                    pg[t][r] = 0.f;
                }
            }
        }
    }

    // atomic split-K epilogue -> out[m][n]  (C/D: m = t*16+quad*4+r, col = ln)
    float* op = out + n0 + wv * 16 + ln;
    #pragma unroll
    for (int t = 0; t < 4; ++t)
        #pragma unroll
        for (int r = 0; r < 4; ++r)
            unsafeAtomicAdd(&op[(size_t)(t * 16 + quad * 4 + r) * Nd], acc[t][r]);
#undef WSTAGE
#undef XLOAD
}

extern "C" void kernel_launch(void* const* d_in, const int* in_sizes, int n_in,
                              void* d_out, int out_size, void* d_ws, size_t ws_size,
                              hipStream_t stream) {
    const float* x     = (const float*)d_in[0];  // [64][4096]
    const float* w     = (const float*)d_in[1];  // [11008][4096]
    const float* scale = (const float*)d_in[2];  // [11008][32]
    const float* bias  = (const float*)d_in[3];  // [11008]
    float* out = (float*)d_out;                  // [64][11008] f32
    float* ws  = (float*)d_ws;                   // xf bf16 (512 KB)

    __bf16* xf = (__bf16*)ws;                    // 16B-aligned

    prep<<<816, 256, 0, stream>>>(x, xf, bias, out);

    dim3 grid1(Nd / BN, KSPLIT);
    qlinear_pass1<<<grid1, 256, 0, stream>>>(w, xf, scale, out);
}